// Round 1
// baseline (296.491 us; speedup 1.0000x reference)
//
#include <hip/hip_runtime.h>
#include <stdint.h>

// ---------------------------------------------------------------------------
// BailingMoE block: T=1024, H=1024, E=16, top-4, I=512 routed, Is=1024 shared
// Strategy: fp32 router (exact top-k), bf16 MFMA GEMMs w/ fp32 accumulation.
// Weights pre-transposed to k-contiguous bf16 in ws (one pass), then
// 64x64-tile GEMMs using v_mfma_f32_16x16x32_bf16.
// ---------------------------------------------------------------------------

typedef __attribute__((ext_vector_type(8))) unsigned short ushort8;
typedef __attribute__((ext_vector_type(4))) float f32x4;
typedef __attribute__((ext_vector_type(8))) __bf16 bf16x8;

#define T_TOK 1024
#define HID   1024
#define NEXP  16
#define TOPK  4
#define MINTER 512
#define SINTER 1024

// ws byte offsets (all 16B aligned where vector-accessed)
constexpr size_t OFF_COUNTS = 0;                               // 16 ints
constexpr size_t OFF_LIST   = 1024;                            // 16*1024 ints
constexpr size_t OFF_WT     = OFF_LIST  + 65536;               // 16*1024 floats
constexpr size_t OFF_SLOT   = OFF_WT    + 65536;               // 16*1024 ints
constexpr size_t OFF_XB     = OFF_SLOT  + 65536;               // bf16 1024x1024
constexpr size_t OFF_HS     = OFF_XB    + 2097152;             // bf16 1024x1024
constexpr size_t OFF_HR     = OFF_HS    + 2097152;             // bf16 4096x512
constexpr size_t OFF_WGT    = OFF_HR    + 4194304;             // bf16 16x512x1024
constexpr size_t OFF_WUT    = OFF_WGT   + 16777216;            // bf16 16x512x1024
constexpr size_t OFF_WDT    = OFF_WUT   + 16777216;            // bf16 16x1024x512
constexpr size_t OFF_WSGUT  = OFF_WDT   + 16777216;            // bf16 2048x1024
constexpr size_t OFF_WSDT   = OFF_WSGUT + 4194304;             // bf16 1024x1024

__device__ __forceinline__ unsigned short f2bf(float f) {
  union { float f; uint32_t u; } v; v.f = f;
  uint32_t r = (v.u + 0x7FFFu + ((v.u >> 16) & 1u)) >> 16;
  return (unsigned short)r;
}
__device__ __forceinline__ bf16x8 as_bf16x8(ushort8 s) {
  union { ushort8 s; bf16x8 b; } u; u.s = s; return u.b;
}
__device__ __forceinline__ float silu(float g) {
  return g / (1.f + __expf(-g));
}

// -------------------------- init: zero expert counts -----------------------
__global__ void init_kernel(int* counts) {
  if (threadIdx.x < NEXP) counts[threadIdx.x] = 0;
}

// -------------------------- router: fp32, one wave per token ---------------
__global__ __launch_bounds__(64) void router_kernel(
    const float* __restrict__ x, const float* __restrict__ rw,
    int* counts, int* list, float* wt, int* slot) {
  const int t = blockIdx.x, l = threadIdx.x;
  float xv[16];
#pragma unroll
  for (int j = 0; j < 16; j++) xv[j] = x[t * HID + j * 64 + l];
  float p[NEXP];
#pragma unroll
  for (int e = 0; e < NEXP; e++) {
    float s = 0.f;
#pragma unroll
    for (int j = 0; j < 16; j++) s += xv[j] * rw[e * HID + j * 64 + l];
#pragma unroll
    for (int off = 32; off > 0; off >>= 1) s += __shfl_xor(s, off);
    p[e] = s;  // all lanes hold full dot product
  }
  // top-4 on logits (monotone w.r.t. softmax probs); ties -> lowest index
  float mx = p[0];
#pragma unroll
  for (int e = 1; e < NEXP; e++) mx = fmaxf(mx, p[e]);
  int idx[TOPK]; float w4[TOPK]; float wsum = 0.f; unsigned used = 0u;
#pragma unroll
  for (int k = 0; k < TOPK; k++) {
    float bv = -1e30f; int bi = 0;
#pragma unroll
    for (int e = 0; e < NEXP; e++)
      if (!((used >> e) & 1u) && p[e] > bv) { bv = p[e]; bi = e; }
    used |= 1u << bi;
    idx[k] = bi;
    w4[k] = __expf(p[bi] - mx);
    wsum += w4[k];
  }
  const float inv = 1.f / wsum;  // softmax denom cancels under top-k renorm
  if (l < TOPK) {
    const int e = idx[l];
    const int pos = atomicAdd(&counts[e], 1);
    list[e * 1024 + pos] = t;
    wt[e * 1024 + pos]   = w4[l] * inv;
    slot[e * 1024 + pos] = t * TOPK + l;
  }
}

// -------------------------- fp32 -> bf16 convert (x) -----------------------
__global__ void convert_bf16_kernel(const float* __restrict__ src,
                                    unsigned short* __restrict__ dst, int n) {
  const int i = (blockIdx.x * blockDim.x + threadIdx.x) * 4;
  if (i + 3 < n) {
    const float4 v = *(const float4*)(src + i);
    dst[i + 0] = f2bf(v.x); dst[i + 1] = f2bf(v.y);
    dst[i + 2] = f2bf(v.z); dst[i + 3] = f2bf(v.w);
  }
}

// ------------------ batched transpose + convert: [b][R][C] -> [b][C][R] ----
__global__ __launch_bounds__(256) void transpose_cvt_kernel(
    const float* __restrict__ src, unsigned short* __restrict__ dst,
    int R, int C) {
  __shared__ float tile[32][33];
  const size_t bo = (size_t)blockIdx.z * R * C;
  src += bo; dst += bo;
  const int c0 = blockIdx.x * 32, r0 = blockIdx.y * 32;
  const int tx = threadIdx.x, ty = threadIdx.y;  // (32, 8)
#pragma unroll
  for (int i = 0; i < 4; i++)
    tile[ty + 8 * i][tx] = src[(size_t)(r0 + ty + 8 * i) * C + c0 + tx];
  __syncthreads();
#pragma unroll
  for (int i = 0; i < 4; i++)
    dst[(size_t)(c0 + ty + 8 * i) * R + r0 + tx] = f2bf(tile[tx][ty + 8 * i]);
}

// ---------------------------------------------------------------------------
// GEMM tiles: BM=BN=64, BK=32, 256 threads (4 waves). LDS rows padded to 40
// ushorts (80B): fragment ds_read_b128 lands 2-way on banks (free, m136).
// Wave w computes rows [16w,16w+16) x all 64 cols as 4 col-tiles.
// ---------------------------------------------------------------------------
#define LDK 40

// shared expert gate/up: Hs[t][i] = silu(X.Wgu[:,i]) * (X.Wgu[:,1024+i])
__global__ __launch_bounds__(256) void shared_gu_kernel(
    const unsigned short* __restrict__ Xb, const unsigned short* __restrict__ WsguT,
    unsigned short* __restrict__ Hs) {
  __shared__ __align__(16) unsigned short sA[64 * LDK];
  __shared__ __align__(16) unsigned short sG[64 * LDK];
  __shared__ __align__(16) unsigned short sU[64 * LDK];
  const int tid = threadIdx.x, wave = tid >> 6, lane = tid & 63;
  const int m0 = blockIdx.y * 64, n0 = blockIdx.x * 64;
  const int sr = tid >> 2, skp = (tid & 3) * 8;
  const unsigned short* gA = Xb   + (size_t)(m0 + sr) * HID + skp;
  const unsigned short* gG = WsguT + (size_t)(n0 + sr) * HID + skp;
  const unsigned short* gU = WsguT + (size_t)(SINTER + n0 + sr) * HID + skp;
  const int sOff = sr * LDK + skp;
  const int aOff = (16 * wave + (lane & 15)) * LDK + (lane >> 4) * 8;
  int bOff[4];
#pragma unroll
  for (int c = 0; c < 4; c++) bOff[c] = (16 * c + (lane & 15)) * LDK + (lane >> 4) * 8;
  f32x4 accG[4], accU[4];
#pragma unroll
  for (int c = 0; c < 4; c++) { accG[c] = (f32x4){0.f,0.f,0.f,0.f}; accU[c] = (f32x4){0.f,0.f,0.f,0.f}; }
  for (int k0 = 0; k0 < HID; k0 += 32) {
    const ushort8 va = *(const ushort8*)(gA + k0);
    const ushort8 vg = *(const ushort8*)(gG + k0);
    const ushort8 vu = *(const ushort8*)(gU + k0);
    __syncthreads();
    *(ushort8*)(sA + sOff) = va;
    *(ushort8*)(sG + sOff) = vg;
    *(ushort8*)(sU + sOff) = vu;
    __syncthreads();
    const bf16x8 af = as_bf16x8(*(const ushort8*)(sA + aOff));
#pragma unroll
    for (int c = 0; c < 4; c++) {
      const bf16x8 gf = as_bf16x8(*(const ushort8*)(sG + bOff[c]));
      const bf16x8 uf = as_bf16x8(*(const ushort8*)(sU + bOff[c]));
      accG[c] = __builtin_amdgcn_mfma_f32_16x16x32_bf16(af, gf, accG[c], 0, 0, 0);
      accU[c] = __builtin_amdgcn_mfma_f32_16x16x32_bf16(af, uf, accU[c], 0, 0, 0);
    }
  }
  const int rb = 16 * wave + (lane >> 4) * 4, cb = lane & 15;
#pragma unroll
  for (int c = 0; c < 4; c++)
#pragma unroll
    for (int r = 0; r < 4; r++) {
      const float h = silu(accG[c][r]) * accU[c][r];
      Hs[(size_t)(m0 + rb + r) * SINTER + n0 + 16 * c + cb] = f2bf(h);
    }
}

// shared expert down: out[t][h] = sum_i Hs[t][i] * Wsd[i][h]  (plain store)
__global__ __launch_bounds__(256) void shared_down_kernel(
    const unsigned short* __restrict__ Hs, const unsigned short* __restrict__ WsdT,
    float* __restrict__ out) {
  __shared__ __align__(16) unsigned short sA[64 * LDK];
  __shared__ __align__(16) unsigned short sB[64 * LDK];
  const int tid = threadIdx.x, wave = tid >> 6, lane = tid & 63;
  const int m0 = blockIdx.y * 64, n0 = blockIdx.x * 64;
  const int sr = tid >> 2, skp = (tid & 3) * 8;
  const unsigned short* gA = Hs   + (size_t)(m0 + sr) * SINTER + skp;
  const unsigned short* gB = WsdT + (size_t)(n0 + sr) * SINTER + skp;
  const int sOff = sr * LDK + skp;
  const int aOff = (16 * wave + (lane & 15)) * LDK + (lane >> 4) * 8;
  int bOff[4];
#pragma unroll
  for (int c = 0; c < 4; c++) bOff[c] = (16 * c + (lane & 15)) * LDK + (lane >> 4) * 8;
  f32x4 acc[4];
#pragma unroll
  for (int c = 0; c < 4; c++) acc[c] = (f32x4){0.f,0.f,0.f,0.f};
  for (int k0 = 0; k0 < SINTER; k0 += 32) {
    const ushort8 va = *(const ushort8*)(gA + k0);
    const ushort8 vb = *(const ushort8*)(gB + k0);
    __syncthreads();
    *(ushort8*)(sA + sOff) = va;
    *(ushort8*)(sB + sOff) = vb;
    __syncthreads();
    const bf16x8 af = as_bf16x8(*(const ushort8*)(sA + aOff));
#pragma unroll
    for (int c = 0; c < 4; c++) {
      const bf16x8 bfr = as_bf16x8(*(const ushort8*)(sB + bOff[c]));
      acc[c] = __builtin_amdgcn_mfma_f32_16x16x32_bf16(af, bfr, acc[c], 0, 0, 0);
    }
  }
  const int rb = 16 * wave + (lane >> 4) * 4, cb = lane & 15;
#pragma unroll
  for (int c = 0; c < 4; c++)
#pragma unroll
    for (int r = 0; r < 4; r++)
      out[(size_t)(m0 + rb + r) * HID + n0 + 16 * c + cb] = acc[c][r];
}

// routed gate/up for expert e over its gathered token rows
__global__ __launch_bounds__(256) void routed_gu_kernel(
    const unsigned short* __restrict__ Xb,
    const unsigned short* __restrict__ WgT, const unsigned short* __restrict__ WuT,
    const int* __restrict__ counts, const int* __restrict__ list,
    const int* __restrict__ slot, unsigned short* __restrict__ Hr) {
  const int e = blockIdx.z;
  const int cnt = counts[e];
  const int m0 = blockIdx.y * 64;
  if (m0 >= cnt) return;
  const int n0 = blockIdx.x * 64;  // I=512 -> 8 tiles
  __shared__ __align__(16) unsigned short sA[64 * LDK];
  __shared__ __align__(16) unsigned short sG[64 * LDK];
  __shared__ __align__(16) unsigned short sU[64 * LDK];
  const int tid = threadIdx.x, wave = tid >> 6, lane = tid & 63;
  const int sr = tid >> 2, skp = (tid & 3) * 8;
  int tok = list[e * 1024 + min(m0 + sr, cnt - 1)];
  tok = min(max(tok, 0), T_TOK - 1);
  const unsigned short* gA = Xb + (size_t)tok * HID + skp;
  const unsigned short* gG = WgT + (size_t)e * MINTER * HID + (size_t)(n0 + sr) * HID + skp;
  const unsigned short* gU = WuT + (size_t)e * MINTER * HID + (size_t)(n0 + sr) * HID + skp;
  const int sOff = sr * LDK + skp;
  const int aOff = (16 * wave + (lane & 15)) * LDK + (lane >> 4) * 8;
  int bOff[4];
#pragma unroll
  for (int c = 0; c < 4; c++) bOff[c] = (16 * c + (lane & 15)) * LDK + (lane >> 4) * 8;
  f32x4 accG[4], accU[4];
#pragma unroll
  for (int c = 0; c < 4; c++) { accG[c] = (f32x4){0.f,0.f,0.f,0.f}; accU[c] = (f32x4){0.f,0.f,0.f,0.f}; }
  for (int k0 = 0; k0 < HID; k0 += 32) {
    const ushort8 va = *(const ushort8*)(gA + k0);
    const ushort8 vg = *(const ushort8*)(gG + k0);
    const ushort8 vu = *(const ushort8*)(gU + k0);
    __syncthreads();
    *(ushort8*)(sA + sOff) = va;
    *(ushort8*)(sG + sOff) = vg;
    *(ushort8*)(sU + sOff) = vu;
    __syncthreads();
    const bf16x8 af = as_bf16x8(*(const ushort8*)(sA + aOff));
#pragma unroll
    for (int c = 0; c < 4; c++) {
      const bf16x8 gf = as_bf16x8(*(const ushort8*)(sG + bOff[c]));
      const bf16x8 uf = as_bf16x8(*(const ushort8*)(sU + bOff[c]));
      accG[c] = __builtin_amdgcn_mfma_f32_16x16x32_bf16(af, gf, accG[c], 0, 0, 0);
      accU[c] = __builtin_amdgcn_mfma_f32_16x16x32_bf16(af, uf, accU[c], 0, 0, 0);
    }
  }
  const int rb = 16 * wave + (lane >> 4) * 4, cb = lane & 15;
#pragma unroll
  for (int c = 0; c < 4; c++)
#pragma unroll
    for (int r = 0; r < 4; r++) {
      const int lrow = rb + r;
      if (m0 + lrow < cnt) {
        const int s = slot[e * 1024 + m0 + lrow];  // valid: t*4+k in [0,4096)
        const float h = silu(accG[c][r]) * accU[c][r];
        Hr[(size_t)s * MINTER + n0 + 16 * c + cb] = f2bf(h);
      }
    }
}

// routed down: out[t][:] += w * (Hr[slot] . Wd[e])   via atomicAdd
__global__ __launch_bounds__(256) void routed_down_kernel(
    const unsigned short* __restrict__ Hr, const unsigned short* __restrict__ WdT,
    const int* __restrict__ counts, const int* __restrict__ list,
    const float* __restrict__ wt, const int* __restrict__ slot,
    float* __restrict__ out) {
  const int e = blockIdx.z;
  const int cnt = counts[e];
  const int m0 = blockIdx.y * 64;
  if (m0 >= cnt) return;
  const int n0 = blockIdx.x * 64;  // H=1024 -> 16 tiles
  __shared__ __align__(16) unsigned short sA[64 * LDK];
  __shared__ __align__(16) unsigned short sB[64 * LDK];
  const int tid = threadIdx.x, wave = tid >> 6, lane = tid & 63;
  const int sr = tid >> 2, skp = (tid & 3) * 8;
  int s = slot[e * 1024 + min(m0 + sr, cnt - 1)];
  s = min(max(s, 0), T_TOK * TOPK - 1);
  const unsigned short* gA = Hr + (size_t)s * MINTER + skp;
  const unsigned short* gB = WdT + (size_t)e * HID * MINTER + (size_t)(n0 + sr) * MINTER + skp;
  const int sOff = sr * LDK + skp;
  const int aOff = (16 * wave + (lane & 15)) * LDK + (lane >> 4) * 8;
  int bOff[4];
#pragma unroll
  for (int c = 0; c < 4; c++) bOff[c] = (16 * c + (lane & 15)) * LDK + (lane >> 4) * 8;
  f32x4 acc[4];
#pragma unroll
  for (int c = 0; c < 4; c++) acc[c] = (f32x4){0.f,0.f,0.f,0.f};
  for (int k0 = 0; k0 < MINTER; k0 += 32) {
    const ushort8 va = *(const ushort8*)(gA + k0);
    const ushort8 vb = *(const ushort8*)(gB + k0);
    __syncthreads();
    *(ushort8*)(sA + sOff) = va;
    *(ushort8*)(sB + sOff) = vb;
    __syncthreads();
    const bf16x8 af = as_bf16x8(*(const ushort8*)(sA + aOff));
#pragma unroll
    for (int c = 0; c < 4; c++) {
      const bf16x8 bfr = as_bf16x8(*(const ushort8*)(sB + bOff[c]));
      acc[c] = __builtin_amdgcn_mfma_f32_16x16x32_bf16(af, bfr, acc[c], 0, 0, 0);
    }
  }
  const int rb = 16 * wave + (lane >> 4) * 4, cb = lane & 15;
#pragma unroll
  for (int c = 0; c < 4; c++)
#pragma unroll
    for (int r = 0; r < 4; r++) {
      const int lrow = rb + r;
      if (m0 + lrow < cnt) {
        const int t = list[e * 1024 + m0 + lrow];
        const float w = wt[e * 1024 + m0 + lrow];
        atomicAdd(out + (size_t)t * HID + n0 + 16 * c + cb, w * acc[c][r]);
      }
    }
}

// ---------------------------------------------------------------------------
extern "C" void kernel_launch(void* const* d_in, const int* in_sizes, int n_in,
                              void* d_out, int out_size, void* d_ws, size_t ws_size,
                              hipStream_t stream) {
  const float* x      = (const float*)d_in[0];
  const float* rw     = (const float*)d_in[1];
  const float* w_gate = (const float*)d_in[2];
  const float* w_up   = (const float*)d_in[3];
  const float* w_down = (const float*)d_in[4];
  const float* ws_gu  = (const float*)d_in[5];
  const float* ws_dn  = (const float*)d_in[6];
  float* out = (float*)d_out;
  char* ws = (char*)d_ws;

  int*   counts = (int*)  (ws + OFF_COUNTS);
  int*   list   = (int*)  (ws + OFF_LIST);
  float* wtbuf  = (float*)(ws + OFF_WT);
  int*   slot   = (int*)  (ws + OFF_SLOT);
  unsigned short* Xb    = (unsigned short*)(ws + OFF_XB);
  unsigned short* Hs    = (unsigned short*)(ws + OFF_HS);
  unsigned short* Hr    = (unsigned short*)(ws + OFF_HR);
  unsigned short* WgT   = (unsigned short*)(ws + OFF_WGT);
  unsigned short* WuT   = (unsigned short*)(ws + OFF_WUT);
  unsigned short* WdT   = (unsigned short*)(ws + OFF_WDT);
  unsigned short* WsguT = (unsigned short*)(ws + OFF_WSGUT);
  unsigned short* WsdT  = (unsigned short*)(ws + OFF_WSDT);

  init_kernel<<<1, 64, 0, stream>>>(counts);
  router_kernel<<<T_TOK, 64, 0, stream>>>(x, rw, counts, list, wtbuf, slot);
  convert_bf16_kernel<<<1024, 256, 0, stream>>>(x, Xb, T_TOK * HID);
  // weights: [b][R][C] fp32 -> [b][C][R] bf16 (k-contiguous for MFMA B-op)
  transpose_cvt_kernel<<<dim3(16, 32, 16), dim3(32, 8), 0, stream>>>(w_gate, WgT, HID, MINTER);
  transpose_cvt_kernel<<<dim3(16, 32, 16), dim3(32, 8), 0, stream>>>(w_up,   WuT, HID, MINTER);
  transpose_cvt_kernel<<<dim3(32, 16, 16), dim3(32, 8), 0, stream>>>(w_down, WdT, MINTER, HID);
  transpose_cvt_kernel<<<dim3(64, 32, 1),  dim3(32, 8), 0, stream>>>(ws_gu,  WsguT, HID, 2 * SINTER);
  transpose_cvt_kernel<<<dim3(32, 32, 1),  dim3(32, 8), 0, stream>>>(ws_dn,  WsdT, SINTER, HID);
  // shared expert (dense): writes out with '='
  shared_gu_kernel<<<dim3(SINTER / 64, T_TOK / 64), 256, 0, stream>>>(Xb, WsguT, Hs);
  shared_down_kernel<<<dim3(HID / 64, T_TOK / 64), 256, 0, stream>>>(Hs, WsdT, out);
  // routed experts: atomicAdd into out (after shared_down)
  routed_gu_kernel<<<dim3(MINTER / 64, T_TOK / 64, NEXP), 256, 0, stream>>>(
      Xb, WgT, WuT, counts, list, slot, Hr);
  routed_down_kernel<<<dim3(HID / 64, T_TOK / 64, NEXP), 256, 0, stream>>>(
      Hr, WdT, counts, list, wtbuf, slot, out);
  (void)in_sizes; (void)n_in; (void)out_size; (void)ws_size;
}